// Round 1
// baseline (152.378 us; speedup 1.0000x reference)
//
#include <hip/hip_runtime.h>

// OHEM cross-entropy: N=8, C=19, H=512, W=1024 (fp32 logits, int32 labels)
#define THRESH     0.35667494393873245f
#define K_KEPT     100000
#define IGNORE_IDX 255
#define C_         19
#define HW_        524288            // 512*1024 (power of 2)
#define LOG_HW     19
#define M_         4194304           // 8 * HW_

// Workspace layout (bytes):
//   [0, 16777216)           loss  (float[M_])
//   [16777216, +131072)     hist1 (u32[32768])  -- top-16-bit histogram
//   [16908288, +262144)     hist2 (u32[65536])  -- low-16-bit refinement
//   [17170432, +64)         scalars: double sum_gt_thresh; double sum_gt_vk;
//                                    u64 cnt_gt_thresh; u32 sel[4]
#define OFF_HIST1  16777216
#define OFF_HIST2  16908288
#define OFF_SCAL   17170432
#define ZERO_BYTES (131072 + 262144 + 64)

// LDS-histogram hot range: bins [15360, 17408) == float values [2^-7, 2^9)
#define HOT_LO 15360u
#define HOT_N  2048u

__global__ __launch_bounds__(256) void ohem_loss_hist(
    const float* __restrict__ logits, const int* __restrict__ labels,
    float* __restrict__ loss, unsigned int* __restrict__ hist1,
    double* __restrict__ sum_gt, unsigned long long* __restrict__ cnt_gt)
{
    __shared__ unsigned int lh[HOT_N];
    for (unsigned int i = threadIdx.x; i < HOT_N; i += 256) lh[i] = 0;
    __syncthreads();

    double lsum = 0.0;
    unsigned int lcnt = 0;

    const int stride = gridDim.x * blockDim.x;
    for (int g = blockIdx.x * blockDim.x + threadIdx.x; g < (M_ / 4); g += stride) {
        const int p0   = g << 2;
        const int n    = p0 >> LOG_HW;
        const int rest = p0 & (HW_ - 1);
        const float* base = logits + (size_t)n * ((size_t)C_ * HW_) + rest;

        // Load all 19 channels x 4 pixels (float4 per channel, coalesced)
        float x[C_][4];
        #pragma unroll
        for (int c = 0; c < C_; ++c) {
            const float4 v = *reinterpret_cast<const float4*>(base + (size_t)c * HW_);
            x[c][0] = v.x; x[c][1] = v.y; x[c][2] = v.z; x[c][3] = v.w;
        }

        const int4 lb4 = *reinterpret_cast<const int4*>(labels + p0);
        const int lb[4] = {lb4.x, lb4.y, lb4.z, lb4.w};
        int cl[4];
        #pragma unroll
        for (int j = 0; j < 4; ++j) cl[j] = min(max(lb[j], 0), C_ - 1);

        float m[4] = {-1e30f, -1e30f, -1e30f, -1e30f};
        #pragma unroll
        for (int c = 0; c < C_; ++c) {
            #pragma unroll
            for (int j = 0; j < 4; ++j) m[j] = fmaxf(m[j], x[c][j]);
        }

        float s[4] = {0.f, 0.f, 0.f, 0.f};
        float xl[4] = {0.f, 0.f, 0.f, 0.f};
        #pragma unroll
        for (int c = 0; c < C_; ++c) {
            #pragma unroll
            for (int j = 0; j < 4; ++j) {
                const float xv = x[c][j];
                s[j] += __expf(xv - m[j]);
                xl[j] = (cl[j] == c) ? xv : xl[j];   // select, no runtime indexing
            }
        }

        float outL[4];
        #pragma unroll
        for (int j = 0; j < 4; ++j) {
            const float nll = __logf(s[j]) + m[j] - xl[j];
            const float L = (lb[j] != IGNORE_IDX) ? fmaxf(nll, 0.f) : 0.f;
            outL[j] = L;
            if (L > THRESH) { lsum += (double)L; ++lcnt; }
            const unsigned int bin = __float_as_uint(L) >> 16;
            if (bin - HOT_LO < HOT_N) atomicAdd(&lh[bin - HOT_LO], 1u);
            else                      atomicAdd(&hist1[bin], 1u);
        }
        float4 ov; ov.x = outL[0]; ov.y = outL[1]; ov.z = outL[2]; ov.w = outL[3];
        *reinterpret_cast<float4*>(loss + p0) = ov;
    }

    __syncthreads();
    for (unsigned int i = threadIdx.x; i < HOT_N; i += 256) {
        const unsigned int v = lh[i];
        if (v) atomicAdd(&hist1[HOT_LO + i], v);
    }

    // block-reduce lsum / lcnt
    for (int off = 32; off > 0; off >>= 1) {
        lsum += __shfl_down(lsum, off);
        lcnt += __shfl_down(lcnt, off);
    }
    __shared__ double       wsum[4];
    __shared__ unsigned int wcnt[4];
    const int wid = threadIdx.x >> 6, lane = threadIdx.x & 63;
    if (lane == 0) { wsum[wid] = lsum; wcnt[wid] = lcnt; }
    __syncthreads();
    if (threadIdx.x == 0) {
        const double s = wsum[0] + wsum[1] + wsum[2] + wsum[3];
        const unsigned long long c = (unsigned long long)wcnt[0] + wcnt[1] + wcnt[2] + wcnt[3];
        atomicAdd(sum_gt, s);
        atomicAdd(cnt_gt, c);
    }
}

// Find coarse bucket b holding descending-rank K_KEPT; sel[0]=b, sel[1]=count(bin>b)
__global__ void ohem_select1(const unsigned int* __restrict__ hist1,
                             unsigned int* __restrict__ sel)
{
    __shared__ unsigned int csum[256];
    unsigned int s = 0;
    const int base = threadIdx.x * 128;
    for (int i = 0; i < 128; ++i) s += hist1[base + i];
    csum[threadIdx.x] = s;
    __syncthreads();
    if (threadIdx.x == 0) {
        const unsigned long long target = (unsigned long long)K_KEPT + 1ull;
        unsigned long long cum = 0;
        int chunk = 0;
        for (int t = 255; t >= 0; --t) {
            if (cum + csum[t] >= target) { chunk = t; break; }
            cum += csum[t];
        }
        int b = chunk * 128;
        for (int i = 127; i >= 0; --i) {
            const unsigned int h = hist1[chunk * 128 + i];
            if (cum + h >= target) { b = chunk * 128 + i; break; }
            cum += h;
        }
        sel[0] = (unsigned int)b;
        sel[1] = (unsigned int)cum;   // elements strictly above bucket b
    }
}

__global__ __launch_bounds__(256) void ohem_hist2(
    const float* __restrict__ loss, const unsigned int* __restrict__ sel,
    unsigned int* __restrict__ hist2)
{
    const unsigned int b = sel[0];
    const int stride = gridDim.x * blockDim.x;
    const uint4* lp = reinterpret_cast<const uint4*>(loss);
    for (int g = blockIdx.x * blockDim.x + threadIdx.x; g < (M_ / 4); g += stride) {
        const uint4 u = lp[g];
        if ((u.x >> 16) == b) atomicAdd(&hist2[u.x & 0xFFFFu], 1u);
        if ((u.y >> 16) == b) atomicAdd(&hist2[u.y & 0xFFFFu], 1u);
        if ((u.z >> 16) == b) atomicAdd(&hist2[u.z & 0xFFFFu], 1u);
        if ((u.w >> 16) == b) atomicAdd(&hist2[u.w & 0xFFFFu], 1u);
    }
}

// Exact order statistic: sel[2] = bits(v_k), sel[3] = count(loss > v_k)
__global__ void ohem_select2(const unsigned int* __restrict__ hist2,
                             unsigned int* __restrict__ sel)
{
    __shared__ unsigned int csum[256];
    unsigned int s = 0;
    const int base = threadIdx.x * 256;
    for (int i = 0; i < 256; ++i) s += hist2[base + i];
    csum[threadIdx.x] = s;
    __syncthreads();
    if (threadIdx.x == 0) {
        const unsigned long long target =
            (unsigned long long)(K_KEPT - sel[1]) + 1ull;
        unsigned long long cum = 0;
        int chunk = 0;
        for (int t = 255; t >= 0; --t) {
            if (cum + csum[t] >= target) { chunk = t; break; }
            cum += csum[t];
        }
        int l = chunk * 256;
        for (int i = 255; i >= 0; --i) {
            const unsigned int h = hist2[chunk * 256 + i];
            if (cum + h >= target) { l = chunk * 256 + i; break; }
            cum += h;
        }
        sel[2] = (sel[0] << 16) | (unsigned int)l;
        sel[3] = sel[1] + (unsigned int)cum;   // strictly greater than v_k
    }
}

__global__ __launch_bounds__(256) void ohem_sumgt(
    const float* __restrict__ loss, const unsigned int* __restrict__ sel,
    double* __restrict__ sum_gt_vk)
{
    const float vk = __uint_as_float(sel[2]);
    double lsum = 0.0;
    const int stride = gridDim.x * blockDim.x;
    const float4* lp = reinterpret_cast<const float4*>(loss);
    for (int g = blockIdx.x * blockDim.x + threadIdx.x; g < (M_ / 4); g += stride) {
        const float4 v = lp[g];
        if (v.x > vk) lsum += (double)v.x;
        if (v.y > vk) lsum += (double)v.y;
        if (v.z > vk) lsum += (double)v.z;
        if (v.w > vk) lsum += (double)v.w;
    }
    for (int off = 32; off > 0; off >>= 1) lsum += __shfl_down(lsum, off);
    __shared__ double wsum[4];
    const int wid = threadIdx.x >> 6, lane = threadIdx.x & 63;
    if (lane == 0) wsum[wid] = lsum;
    __syncthreads();
    if (threadIdx.x == 0)
        atomicAdd(sum_gt_vk, wsum[0] + wsum[1] + wsum[2] + wsum[3]);
}

__global__ void ohem_finalize(const unsigned int* __restrict__ sel,
                              const double* __restrict__ sum_gt,
                              const unsigned long long* __restrict__ cnt_gt,
                              const double* __restrict__ sum_gt_vk,
                              float* __restrict__ out)
{
    if (threadIdx.x == 0) {
        const float vk = __uint_as_float(sel[2]);
        double r;
        if (vk > THRESH) {
            r = sum_gt[0] / (double)cnt_gt[0];
        } else {
            const unsigned int c = sel[3];   // c <= K_KEPT by construction
            r = (sum_gt_vk[0] + (double)(K_KEPT - (long long)c) * (double)vk)
                / (double)K_KEPT;
        }
        out[0] = (float)r;
    }
}

extern "C" void kernel_launch(void* const* d_in, const int* in_sizes, int n_in,
                              void* d_out, int out_size, void* d_ws, size_t ws_size,
                              hipStream_t stream)
{
    const float* logits = (const float*)d_in[0];
    const int*   labels = (const int*)d_in[1];
    float* out = (float*)d_out;

    char* ws = (char*)d_ws;
    float*              loss      = (float*)ws;
    unsigned int*       hist1     = (unsigned int*)(ws + OFF_HIST1);
    unsigned int*       hist2     = (unsigned int*)(ws + OFF_HIST2);
    char*               scal      = ws + OFF_SCAL;
    double*             sum_gt    = (double*)(scal + 0);
    double*             sum_gt_vk = (double*)(scal + 8);
    unsigned long long* cnt_gt    = (unsigned long long*)(scal + 16);
    unsigned int*       sel       = (unsigned int*)(scal + 24);

    hipMemsetAsync(hist1, 0, ZERO_BYTES, stream);

    ohem_loss_hist<<<256, 256, 0, stream>>>(logits, labels, loss, hist1, sum_gt, cnt_gt);
    ohem_select1 <<<1, 256, 0, stream>>>(hist1, sel);
    ohem_hist2   <<<256, 256, 0, stream>>>(loss, sel, hist2);
    ohem_select2 <<<1, 256, 0, stream>>>(hist2, sel);
    ohem_sumgt   <<<256, 256, 0, stream>>>(loss, sel, sum_gt_vk);
    ohem_finalize<<<1, 64, 0, stream>>>(sel, sum_gt, cnt_gt, sum_gt_vk, out);
}